// Round 2
// baseline (1519.650 us; speedup 1.0000x reference)
//
#include <hip/hip_runtime.h>
#include <cmath>

// ---------------------------------------------------------------------------
// NonLocalBlock, fp32 end-to-end (round 0: correctness + reasonable tiling)
// x:[8,512,64,64]  g/theta/phi: Cint=256 1x1 convs; g,phi maxpool2 -> M=1024
// f = softmax(theta^T phi) ; y = f @ g^T ; z = W(y)+BN+residual
// ---------------------------------------------------------------------------

#define B_  8
#define C_  512
#define CI_ 256
#define N_  4096   // 64*64
#define M_  1024   // 32*32

// ===========================================================================
// K1: projections. Computes [768,512] @ x_b[512,4096] per batch.
// blockIdx.y in [0,12): /4 -> which projection (0=g,1=theta,2=phi), %4 -> 64-row tile
// Tile: BM=64 (out rows), BN=128 (spatial, = two image rows), BK=32.
// g/phi epilogue: fused 2x2 maxpool -> [256,1024].
// ===========================================================================
__global__ __launch_bounds__(256) void proj_kernel(
    const float* __restrict__ x,
    const float* __restrict__ g_w,  const float* __restrict__ g_b,
    const float* __restrict__ th_w, const float* __restrict__ th_b,
    const float* __restrict__ ph_w, const float* __restrict__ ph_b,
    float* __restrict__ theta, float* __restrict__ gp, float* __restrict__ php)
{
    __shared__ float As[64][36];     // [row][k], +4 pad
    __shared__ float Bs[32][128];    // [k][n]
    __shared__ float poolbuf[64][32];

    const int tx = threadIdx.x, ty = threadIdx.y;
    const int tid = ty * 16 + tx;
    const int bx = blockIdx.x, by = blockIdx.y, b = blockIdx.z;
    const int proj = by >> 2;
    const int r0 = (by & 3) * 64;
    const int n0 = bx * 128;

    const float* Wp = (proj == 0) ? g_w : (proj == 1) ? th_w : ph_w;
    const float* Bp = (proj == 0) ? g_b : (proj == 1) ? th_b : ph_b;

    float acc[4][8];
    #pragma unroll
    for (int i = 0; i < 4; ++i)
        #pragma unroll
        for (int j = 0; j < 8; ++j) acc[i][j] = 0.f;

    const int ao = tid >> 2, aq = tid & 3;        // A: row, k-octet
    const int bkr = tid >> 5, bc = (tid & 31) * 4; // B: k-row base, col

    for (int k0 = 0; k0 < C_; k0 += 32) {
        *(float4*)&As[ao][aq * 8]     = *(const float4*)&Wp[(size_t)(r0 + ao) * C_ + k0 + aq * 8];
        *(float4*)&As[ao][aq * 8 + 4] = *(const float4*)&Wp[(size_t)(r0 + ao) * C_ + k0 + aq * 8 + 4];
        #pragma unroll
        for (int i = 0; i < 4; ++i) {
            const int kk = bkr + i * 8;
            *(float4*)&Bs[kk][bc] = *(const float4*)&x[((size_t)b * C_ + k0 + kk) * N_ + n0 + bc];
        }
        __syncthreads();
        #pragma unroll
        for (int k = 0; k < 32; ++k) {
            float a[4];
            #pragma unroll
            for (int i = 0; i < 4; ++i) a[i] = As[ty * 4 + i][k];
            const float4 b0 = *(const float4*)&Bs[k][tx * 8];
            const float4 b1 = *(const float4*)&Bs[k][tx * 8 + 4];
            const float bb[8] = {b0.x, b0.y, b0.z, b0.w, b1.x, b1.y, b1.z, b1.w};
            #pragma unroll
            for (int i = 0; i < 4; ++i)
                #pragma unroll
                for (int j = 0; j < 8; ++j)
                    acc[i][j] = fmaf(a[i], bb[j], acc[i][j]);
        }
        __syncthreads();
    }

    #pragma unroll
    for (int i = 0; i < 4; ++i) {
        const float bias = Bp[r0 + ty * 4 + i];
        #pragma unroll
        for (int j = 0; j < 8; ++j) acc[i][j] += bias;
    }

    if (proj == 1) {
        // theta: direct [B][256][4096]
        #pragma unroll
        for (int i = 0; i < 4; ++i) {
            const size_t base = ((size_t)b * CI_ + r0 + ty * 4 + i) * N_ + n0 + tx * 8;
            float4 v0 = {acc[i][0], acc[i][1], acc[i][2], acc[i][3]};
            float4 v1 = {acc[i][4], acc[i][5], acc[i][6], acc[i][7]};
            *(float4*)&theta[base]     = v0;
            *(float4*)&theta[base + 4] = v1;
        }
    } else {
        // g / phi: 2x2 maxpool. Tile covers image rows h=2*bx, 2*bx+1.
        // tx<8 threads hold top row (n local < 64), tx>=8 bottom row.
        float* outp = (proj == 0) ? gp : php;
        #pragma unroll
        for (int i = 0; i < 4; ++i)
            #pragma unroll
            for (int j2 = 0; j2 < 4; ++j2) {
                const float h = fmaxf(acc[i][2 * j2], acc[i][2 * j2 + 1]);
                if (tx < 8) poolbuf[ty * 4 + i][tx * 4 + j2] = h;
            }
        __syncthreads();
        if (tx >= 8) {
            #pragma unroll
            for (int i = 0; i < 4; ++i)
                #pragma unroll
                for (int j2 = 0; j2 < 4; ++j2) {
                    const float h = fmaxf(acc[i][2 * j2], acc[i][2 * j2 + 1]);
                    const float v = fmaxf(h, poolbuf[ty * 4 + i][(tx - 8) * 4 + j2]);
                    outp[((size_t)b * CI_ + r0 + ty * 4 + i) * M_ + bx * 32 + (tx - 8) * 4 + j2] = v;
                }
        }
    }
}

// ===========================================================================
// K2: flash attention. Per block: 32 query rows (n), loop 16 m-tiles of 64.
// S[n,m] = sum_c theta[c,n]*phi[c,m]; online softmax; Y[n,ci] += P @ G^T.
// Thread (tx,ty): n rows = ty*2+{0,1}; ci = tx + 16*i (i=0..15). Y in regs.
// ===========================================================================
__global__ __launch_bounds__(256) void attn_kernel(
    const float* __restrict__ theta, const float* __restrict__ php,
    const float* __restrict__ gp, float* __restrict__ y)
{
    __shared__ float Tlds[256][32];   // theta [c][n_local]
    __shared__ float Phlds[32][64];   // phi k-chunk [k][m]
    __shared__ float Plds[32][68];    // P [n][m] (+4 pad)
    __shared__ float Glds[64][68];    // G chunk [ci_local][m] (+4 pad)

    const int tx = threadIdx.x, ty = threadIdx.y;
    const int tid = ty * 16 + tx;
    const int n0 = blockIdx.x * 32;
    const int b = blockIdx.y;

    {   // stage theta block [256][32]
        const int c0 = tid >> 3, mq = tid & 7;
        #pragma unroll
        for (int it = 0; it < 8; ++it) {
            const int c = c0 + it * 32;
            *(float4*)&Tlds[c][mq * 4] =
                *(const float4*)&theta[((size_t)b * CI_ + c) * N_ + n0 + mq * 4];
        }
    }
    __syncthreads();

    float yacc[2][16];
    #pragma unroll
    for (int r = 0; r < 2; ++r)
        #pragma unroll
        for (int i = 0; i < 16; ++i) yacc[r][i] = 0.f;
    float m_run[2] = {-INFINITY, -INFINITY};
    float l_run[2] = {0.f, 0.f};

    const int pk = tid >> 3, pq = tid & 7;   // phi staging
    const int gr = tid >> 4, gq = tid & 15;  // g staging

    for (int mt = 0; mt < 16; ++mt) {
        const int m0 = mt * 64;
        float sacc[2][4] = {{0, 0, 0, 0}, {0, 0, 0, 0}};

        // ---- S = theta^T phi, K=256 in chunks of 32 ----
        for (int kc = 0; kc < 8; ++kc) {
            const int k0 = kc * 32;
            const size_t pbase = ((size_t)b * CI_ + k0 + pk) * M_ + m0 + pq * 8;
            *(float4*)&Phlds[pk][pq * 8]     = *(const float4*)&php[pbase];
            *(float4*)&Phlds[pk][pq * 8 + 4] = *(const float4*)&php[pbase + 4];
            __syncthreads();
            #pragma unroll
            for (int k = 0; k < 32; ++k) {
                const float2 t2 = *(const float2*)&Tlds[k0 + k][ty * 2];
                const float4 p4 = *(const float4*)&Phlds[k][tx * 4];
                const float pp[4] = {p4.x, p4.y, p4.z, p4.w};
                #pragma unroll
                for (int j = 0; j < 4; ++j) {
                    sacc[0][j] = fmaf(t2.x, pp[j], sacc[0][j]);
                    sacc[1][j] = fmaf(t2.y, pp[j], sacc[1][j]);
                }
            }
            __syncthreads();
        }

        // ---- online softmax over this m-tile ----
        #pragma unroll
        for (int r = 0; r < 2; ++r) {
            float v = fmaxf(fmaxf(sacc[r][0], sacc[r][1]), fmaxf(sacc[r][2], sacc[r][3]));
            #pragma unroll
            for (int off = 1; off < 16; off <<= 1) v = fmaxf(v, __shfl_xor(v, off, 64));
            const float mnew = fmaxf(m_run[r], v);
            const float sc = __expf(m_run[r] - mnew);
            float s = 0.f;
            #pragma unroll
            for (int j = 0; j < 4; ++j) {
                const float p = __expf(sacc[r][j] - mnew);
                Plds[ty * 2 + r][tx * 4 + j] = p;
                s += p;
            }
            #pragma unroll
            for (int off = 1; off < 16; off <<= 1) s += __shfl_xor(s, off, 64);
            l_run[r] = l_run[r] * sc + s;
            m_run[r] = mnew;
            #pragma unroll
            for (int i = 0; i < 16; ++i) yacc[r][i] *= sc;
        }
        __syncthreads();  // Plds visible

        // ---- Y += P @ G^T, ci in 4 chunks of 64 ----
        for (int cc = 0; cc < 4; ++cc) {
            #pragma unroll
            for (int i = 0; i < 4; ++i) {
                const int cil = gr + i * 16;
                *(float4*)&Glds[cil][gq * 4] =
                    *(const float4*)&gp[((size_t)b * CI_ + cc * 64 + cil) * M_ + m0 + gq * 4];
            }
            __syncthreads();
            #pragma unroll
            for (int m4 = 0; m4 < 16; ++m4) {
                const float4 pa = *(const float4*)&Plds[ty * 2][m4 * 4];
                const float4 pb = *(const float4*)&Plds[ty * 2 + 1][m4 * 4];
                #pragma unroll
                for (int ii = 0; ii < 4; ++ii) {
                    const float4 g = *(const float4*)&Glds[tx + 16 * ii][m4 * 4];
                    const int idx = cc * 4 + ii;
                    yacc[0][idx] += pa.x * g.x + pa.y * g.y + pa.z * g.z + pa.w * g.w;
                    yacc[1][idx] += pb.x * g.x + pb.y * g.y + pb.z * g.z + pb.w * g.w;
                }
            }
            __syncthreads();
        }
    }

    // ---- normalize and store y [B][256][4096] ----
    #pragma unroll
    for (int r = 0; r < 2; ++r) {
        const float inv = 1.f / l_run[r];
        #pragma unroll
        for (int i = 0; i < 16; ++i) {
            const int ci = tx + 16 * i;
            y[((size_t)b * CI_ + ci) * N_ + n0 + ty * 2 + r] = yacc[r][i] * inv;
        }
    }
}

// ===========================================================================
// K3: z = W[512,256] @ y + b, BN (inference), + residual x.
// ===========================================================================
__global__ __launch_bounds__(256) void out_kernel(
    const float* __restrict__ y, const float* __restrict__ w_w, const float* __restrict__ w_b,
    const float* __restrict__ bn_g, const float* __restrict__ bn_b,
    const float* __restrict__ bn_m, const float* __restrict__ bn_v,
    const float* __restrict__ x, float* __restrict__ out)
{
    __shared__ float As[64][36];
    __shared__ float Bs[32][128];

    const int tx = threadIdx.x, ty = threadIdx.y;
    const int tid = ty * 16 + tx;
    const int bx = blockIdx.x, by = blockIdx.y, b = blockIdx.z;
    const int r0 = by * 64, n0 = bx * 128;

    float acc[4][8];
    #pragma unroll
    for (int i = 0; i < 4; ++i)
        #pragma unroll
        for (int j = 0; j < 8; ++j) acc[i][j] = 0.f;

    const int ao = tid >> 2, aq = tid & 3;
    const int bkr = tid >> 5, bc = (tid & 31) * 4;

    for (int k0 = 0; k0 < CI_; k0 += 32) {
        *(float4*)&As[ao][aq * 8]     = *(const float4*)&w_w[(size_t)(r0 + ao) * CI_ + k0 + aq * 8];
        *(float4*)&As[ao][aq * 8 + 4] = *(const float4*)&w_w[(size_t)(r0 + ao) * CI_ + k0 + aq * 8 + 4];
        #pragma unroll
        for (int i = 0; i < 4; ++i) {
            const int kk = bkr + i * 8;
            *(float4*)&Bs[kk][bc] = *(const float4*)&y[((size_t)b * CI_ + k0 + kk) * N_ + n0 + bc];
        }
        __syncthreads();
        #pragma unroll
        for (int k = 0; k < 32; ++k) {
            float a[4];
            #pragma unroll
            for (int i = 0; i < 4; ++i) a[i] = As[ty * 4 + i][k];
            const float4 b0 = *(const float4*)&Bs[k][tx * 8];
            const float4 b1 = *(const float4*)&Bs[k][tx * 8 + 4];
            const float bb[8] = {b0.x, b0.y, b0.z, b0.w, b1.x, b1.y, b1.z, b1.w};
            #pragma unroll
            for (int i = 0; i < 4; ++i)
                #pragma unroll
                for (int j = 0; j < 8; ++j)
                    acc[i][j] = fmaf(a[i], bb[j], acc[i][j]);
        }
        __syncthreads();
    }

    #pragma unroll
    for (int i = 0; i < 4; ++i) {
        const int c = r0 + ty * 4 + i;
        const float sc = bn_g[c] * rsqrtf(bn_v[c] + 1e-5f);
        const float bb = bn_b[c], mn = bn_m[c], wb = w_b[c];
        const size_t base = ((size_t)b * C_ + c) * N_ + n0 + tx * 8;
        const float4 x0 = *(const float4*)&x[base];
        const float4 x1 = *(const float4*)&x[base + 4];
        const float xr[8] = {x0.x, x0.y, x0.z, x0.w, x1.x, x1.y, x1.z, x1.w};
        float o[8];
        #pragma unroll
        for (int j = 0; j < 8; ++j)
            o[j] = fmaf(acc[i][j] + wb - mn, sc, bb) + xr[j];
        float4 v0 = {o[0], o[1], o[2], o[3]};
        float4 v1 = {o[4], o[5], o[6], o[7]};
        *(float4*)&out[base]     = v0;
        *(float4*)&out[base + 4] = v1;
    }
}

// ===========================================================================
extern "C" void kernel_launch(void* const* d_in, const int* in_sizes, int n_in,
                              void* d_out, int out_size, void* d_ws, size_t ws_size,
                              hipStream_t stream) {
    const float* x    = (const float*)d_in[0];
    const float* g_w  = (const float*)d_in[1];
    const float* g_b  = (const float*)d_in[2];
    const float* th_w = (const float*)d_in[3];
    const float* th_b = (const float*)d_in[4];
    const float* ph_w = (const float*)d_in[5];
    const float* ph_b = (const float*)d_in[6];
    const float* w_w  = (const float*)d_in[7];
    const float* w_b  = (const float*)d_in[8];
    const float* bn_g = (const float*)d_in[9];
    const float* bn_b = (const float*)d_in[10];
    const float* bn_m = (const float*)d_in[11];
    const float* bn_v = (const float*)d_in[12];
    float* out = (float*)d_out;

    float* ws    = (float*)d_ws;
    float* theta = ws;                                   // 8*256*4096 = 8388608 f
    float* gp    = theta + (size_t)B_ * CI_ * N_;        // 8*256*1024 = 2097152 f
    float* php   = gp + (size_t)B_ * CI_ * M_;           // 2097152 f
    float* yb    = php + (size_t)B_ * CI_ * M_;          // 8388608 f  (total 80 MB)

    dim3 blk(16, 16);
    proj_kernel<<<dim3(32, 12, 8), blk, 0, stream>>>(x, g_w, g_b, th_w, th_b, ph_w, ph_b,
                                                     theta, gp, php);
    attn_kernel<<<dim3(128, 8), blk, 0, stream>>>(theta, php, gp, yb);
    out_kernel<<<dim3(32, 8, 8), blk, 0, stream>>>(yb, w_w, w_b, bn_g, bn_b, bn_m, bn_v,
                                                   x, out);
}

// Round 3
// 874.376 us; speedup vs baseline: 1.7380x; 1.7380x over previous
//
#include <hip/hip_runtime.h>
#include <cmath>

// ---------------------------------------------------------------------------
// NonLocalBlock. Round 3: attention on f16 MFMA (fp32 accum), projections
// fp32 VALU but emitting fp16 MFMA-ready layouts:
//   thT[b][n][c]  (theta^T, c contiguous)   phT[b][m][c]  (phi^T, c contiguous)
//   g16[b][ci][m] (m contiguous)            y[b][ci][n] fp32 (unchanged for K3)
// ---------------------------------------------------------------------------

#define B_  8
#define C_  512
#define CI_ 256
#define N_  4096   // 64*64
#define M_  1024   // 32*32

typedef _Float16 half8 __attribute__((ext_vector_type(8)));
typedef _Float16 half4 __attribute__((ext_vector_type(4)));
typedef float    f32x4 __attribute__((ext_vector_type(4)));

// ===========================================================================
// K1: projections [768,512] @ x_b[512,4096], fp32 compute, fp16 outputs.
// blockIdx.y: /4 -> proj (0=g,1=theta,2=phi), %4 -> 64-row tile.
// g/phi: fused 2x2 maxpool -> M=1024.
// ===========================================================================
__global__ __launch_bounds__(256) void proj_kernel(
    const float* __restrict__ x,
    const float* __restrict__ g_w,  const float* __restrict__ g_b,
    const float* __restrict__ th_w, const float* __restrict__ th_b,
    const float* __restrict__ ph_w, const float* __restrict__ ph_b,
    _Float16* __restrict__ thT, _Float16* __restrict__ phT, _Float16* __restrict__ g16)
{
    __shared__ float As[64][36];
    __shared__ float Bs[32][128];
    __shared__ float poolbuf[64][32];

    const int tx = threadIdx.x, ty = threadIdx.y;
    const int tid = ty * 16 + tx;
    const int bx = blockIdx.x, by = blockIdx.y, b = blockIdx.z;
    const int proj = by >> 2;
    const int r0 = (by & 3) * 64;
    const int n0 = bx * 128;

    const float* Wp = (proj == 0) ? g_w : (proj == 1) ? th_w : ph_w;
    const float* Bp = (proj == 0) ? g_b : (proj == 1) ? th_b : ph_b;

    float acc[4][8];
    #pragma unroll
    for (int i = 0; i < 4; ++i)
        #pragma unroll
        for (int j = 0; j < 8; ++j) acc[i][j] = 0.f;

    const int ao = tid >> 2, aq = tid & 3;
    const int bkr = tid >> 5, bc = (tid & 31) * 4;

    for (int k0 = 0; k0 < C_; k0 += 32) {
        *(float4*)&As[ao][aq * 8]     = *(const float4*)&Wp[(size_t)(r0 + ao) * C_ + k0 + aq * 8];
        *(float4*)&As[ao][aq * 8 + 4] = *(const float4*)&Wp[(size_t)(r0 + ao) * C_ + k0 + aq * 8 + 4];
        #pragma unroll
        for (int i = 0; i < 4; ++i) {
            const int kk = bkr + i * 8;
            *(float4*)&Bs[kk][bc] = *(const float4*)&x[((size_t)b * C_ + k0 + kk) * N_ + n0 + bc];
        }
        __syncthreads();
        #pragma unroll
        for (int k = 0; k < 32; ++k) {
            float a[4];
            #pragma unroll
            for (int i = 0; i < 4; ++i) a[i] = As[ty * 4 + i][k];
            const float4 b0 = *(const float4*)&Bs[k][tx * 8];
            const float4 b1 = *(const float4*)&Bs[k][tx * 8 + 4];
            const float bb[8] = {b0.x, b0.y, b0.z, b0.w, b1.x, b1.y, b1.z, b1.w};
            #pragma unroll
            for (int i = 0; i < 4; ++i)
                #pragma unroll
                for (int j = 0; j < 8; ++j)
                    acc[i][j] = fmaf(a[i], bb[j], acc[i][j]);
        }
        __syncthreads();
    }

    #pragma unroll
    for (int i = 0; i < 4; ++i) {
        const float bias = Bp[r0 + ty * 4 + i];
        #pragma unroll
        for (int j = 0; j < 8; ++j) acc[i][j] += bias;
    }

    if (proj == 1) {
        // theta^T: [b][n][c] fp16, pack 4 consecutive c per store
        #pragma unroll
        for (int j = 0; j < 8; ++j) {
            const int n = n0 + tx * 8 + j;
            half4 hv = { (_Float16)acc[0][j], (_Float16)acc[1][j],
                         (_Float16)acc[2][j], (_Float16)acc[3][j] };
            *(half4*)&thT[((size_t)b * N_ + n) * CI_ + r0 + ty * 4] = hv;
        }
    } else {
        // g / phi: 2x2 maxpool (tile = image rows 2bx, 2bx+1)
        #pragma unroll
        for (int i = 0; i < 4; ++i)
            #pragma unroll
            for (int j2 = 0; j2 < 4; ++j2) {
                const float h = fmaxf(acc[i][2 * j2], acc[i][2 * j2 + 1]);
                if (tx < 8) poolbuf[ty * 4 + i][tx * 4 + j2] = h;
            }
        __syncthreads();
        if (tx >= 8) {
            float v[4][4];
            #pragma unroll
            for (int i = 0; i < 4; ++i)
                #pragma unroll
                for (int j2 = 0; j2 < 4; ++j2) {
                    const float h = fmaxf(acc[i][2 * j2], acc[i][2 * j2 + 1]);
                    v[i][j2] = fmaxf(h, poolbuf[ty * 4 + i][(tx - 8) * 4 + j2]);
                }
            if (proj == 0) {
                // g: [b][ci][m], pack 4 consecutive m
                #pragma unroll
                for (int i = 0; i < 4; ++i) {
                    const int c = r0 + ty * 4 + i;
                    half4 hv = { (_Float16)v[i][0], (_Float16)v[i][1],
                                 (_Float16)v[i][2], (_Float16)v[i][3] };
                    *(half4*)&g16[((size_t)b * CI_ + c) * M_ + bx * 32 + (tx - 8) * 4] = hv;
                }
            } else {
                // phi^T: [b][m][c], pack 4 consecutive c
                #pragma unroll
                for (int j2 = 0; j2 < 4; ++j2) {
                    const int m = bx * 32 + (tx - 8) * 4 + j2;
                    half4 hv = { (_Float16)v[0][j2], (_Float16)v[1][j2],
                                 (_Float16)v[2][j2], (_Float16)v[3][j2] };
                    *(half4*)&phT[((size_t)b * M_ + m) * CI_ + r0 + ty * 4] = hv;
                }
            }
        }
    }
}

// ===========================================================================
// K2: flash attention on mfma_f32_16x16x32_f16.
// Block: 256 thr = 4 waves; QBLK=64 (wave w owns n rows w*16..w*16+15).
// Loop 16 m-tiles of 64: S-chunks over c (4x64), online softmax, PV chunks
// over ci (4x64). Frag layouts: A row=l&15 k=(l>>4)*8+i; B col=l&15 same k;
// C/D col=l&15 row=(l>>4)*4+reg.
// LDS 61440 B -> 2 blocks/CU.
// ===========================================================================
__global__ __launch_bounds__(256) void attn_kernel(
    const _Float16* __restrict__ thT, const _Float16* __restrict__ phT,
    const _Float16* __restrict__ g16, float* __restrict__ y)
{
    __shared__ __align__(16) char smem[61440];
    _Float16 (*Tl)[264] = (_Float16(*)[264])smem;                 // 64x264 f16 = 33792 B
    _Float16 (*Ph)[72]  = (_Float16(*)[72])(smem + 33792);        // 64x72  f16 =  9216 B
    _Float16 (*Gl)[72]  = (_Float16(*)[72])(smem + 43008);        // 64x72  f16 =  9216 B
    _Float16 (*Pl)[72]  = (_Float16(*)[72])(smem + 52224);        // 64x72  f16 =  9216 B
    float    (*Yb)[69]  = (float(*)[69])(smem + 33792);           // 64x69 f32 = 17664 B (overlays Ph+Gl)

    const int t = threadIdx.x;
    const int w = t >> 6, l = t & 63;
    const int l15 = l & 15, lg = l >> 4;
    const int n0 = blockIdx.x * 64;
    const int b  = blockIdx.y;

    // ---- stage theta^T tile [64 n][256 c] once ----
    {
        const int row = t >> 2, cq = (t & 3) * 64;
        const _Float16* src = &thT[((size_t)b * N_ + n0 + row) * CI_ + cq];
        #pragma unroll
        for (int i = 0; i < 8; ++i)
            *(half8*)&Tl[row][cq + 8 * i] = *(const half8*)&src[8 * i];
    }

    f32x4 yacc[16];
    #pragma unroll
    for (int i = 0; i < 16; ++i) yacc[i] = (f32x4){0.f, 0.f, 0.f, 0.f};
    float m_run[4] = {-INFINITY, -INFINITY, -INFINITY, -INFINITY};
    float l_run[4] = {0.f, 0.f, 0.f, 0.f};

    const int srow = t >> 2, ssq = (t & 3) * 16;   // cooperative staging coords

    #pragma unroll 1
    for (int mt = 0; mt < 16; ++mt) {
        const int m0 = mt * 64;
        f32x4 sf[4];
        #pragma unroll
        for (int i = 0; i < 4; ++i) sf[i] = (f32x4){0.f, 0.f, 0.f, 0.f};

        // ---- S = theta^T phi over c in 4 chunks of 64 ----
        #pragma unroll 1
        for (int cch = 0; cch < 4; ++cch) {
            __syncthreads();
            const _Float16* src = &phT[((size_t)b * M_ + m0 + srow) * CI_ + cch * 64 + ssq];
            *(half8*)&Ph[srow][ssq]     = *(const half8*)&src[0];
            *(half8*)&Ph[srow][ssq + 8] = *(const half8*)&src[8];
            __syncthreads();
            #pragma unroll
            for (int ks = 0; ks < 2; ++ks) {
                half8 a = *(half8*)&Tl[w * 16 + l15][cch * 64 + ks * 32 + lg * 8];
                #pragma unroll
                for (int mf = 0; mf < 4; ++mf) {
                    half8 bb = *(half8*)&Ph[mf * 16 + l15][ks * 32 + lg * 8];
                    sf[mf] = __builtin_amdgcn_mfma_f32_16x16x32_f16(a, bb, sf[mf], 0, 0, 0);
                }
            }
        }

        // ---- online softmax (rows r: n = lg*4+r) ----
        float sc[4];
        #pragma unroll
        for (int r = 0; r < 4; ++r) {
            float mx = fmaxf(fmaxf(sf[0][r], sf[1][r]), fmaxf(sf[2][r], sf[3][r]));
            #pragma unroll
            for (int off = 1; off < 16; off <<= 1) mx = fmaxf(mx, __shfl_xor(mx, off, 64));
            const float mnew = fmaxf(m_run[r], mx);
            sc[r] = __expf(m_run[r] - mnew);
            float sum = 0.f;
            #pragma unroll
            for (int mf = 0; mf < 4; ++mf) {
                const float p = __expf(sf[mf][r] - mnew);
                Pl[w * 16 + lg * 4 + r][mf * 16 + l15] = (_Float16)p;
                sum += p;
            }
            #pragma unroll
            for (int off = 1; off < 16; off <<= 1) sum += __shfl_xor(sum, off, 64);
            l_run[r] = l_run[r] * sc[r] + sum;
            m_run[r] = mnew;
        }
        #pragma unroll
        for (int i = 0; i < 16; ++i) {
            yacc[i][0] *= sc[0]; yacc[i][1] *= sc[1];
            yacc[i][2] *= sc[2]; yacc[i][3] *= sc[3];
        }

        // ---- Y += P @ G^T over ci in 4 chunks of 64 ----
        #pragma unroll 1
        for (int cc = 0; cc < 4; ++cc) {
            __syncthreads();
            const _Float16* gs = &g16[((size_t)b * CI_ + cc * 64 + srow) * M_ + m0 + ssq];
            *(half8*)&Gl[srow][ssq]     = *(const half8*)&gs[0];
            *(half8*)&Gl[srow][ssq + 8] = *(const half8*)&gs[8];
            __syncthreads();
            half8 pa0 = *(half8*)&Pl[w * 16 + l15][lg * 8];
            half8 pa1 = *(half8*)&Pl[w * 16 + l15][32 + lg * 8];
            #pragma unroll
            for (int cf = 0; cf < 4; ++cf) {
                half8 b0 = *(half8*)&Gl[cf * 16 + l15][lg * 8];
                half8 b1 = *(half8*)&Gl[cf * 16 + l15][32 + lg * 8];
                yacc[cc * 4 + cf] = __builtin_amdgcn_mfma_f32_16x16x32_f16(pa0, b0, yacc[cc * 4 + cf], 0, 0, 0);
                yacc[cc * 4 + cf] = __builtin_amdgcn_mfma_f32_16x16x32_f16(pa1, b1, yacc[cc * 4 + cf], 0, 0, 0);
            }
        }
    }

    // ---- epilogue: y[b][ci][n] fp32, coalesced via LDS transpose ----
    float linv[4];
    #pragma unroll
    for (int r = 0; r < 4; ++r) linv[r] = 1.f / l_run[r];
    const int nl = t & 63, cb = (t >> 6) * 16;
    #pragma unroll 1
    for (int cq = 0; cq < 4; ++cq) {
        __syncthreads();
        #pragma unroll
        for (int f = 0; f < 4; ++f)
            #pragma unroll
            for (int r = 0; r < 4; ++r)
                Yb[w * 16 + lg * 4 + r][f * 16 + l15] = yacc[cq * 4 + f][r] * linv[r];
        __syncthreads();
        #pragma unroll
        for (int j = 0; j < 16; ++j)
            y[((size_t)b * CI_ + cq * 64 + cb + j) * N_ + n0 + nl] = Yb[nl][cb + j];
    }
}

// ===========================================================================
// K3: z = W[512,256] @ y + b, BN (inference), + residual x.  (unchanged)
// ===========================================================================
__global__ __launch_bounds__(256) void out_kernel(
    const float* __restrict__ y, const float* __restrict__ w_w, const float* __restrict__ w_b,
    const float* __restrict__ bn_g, const float* __restrict__ bn_b,
    const float* __restrict__ bn_m, const float* __restrict__ bn_v,
    const float* __restrict__ x, float* __restrict__ out)
{
    __shared__ float As[64][36];
    __shared__ float Bs[32][128];

    const int tx = threadIdx.x, ty = threadIdx.y;
    const int tid = ty * 16 + tx;
    const int bx = blockIdx.x, by = blockIdx.y, b = blockIdx.z;
    const int r0 = by * 64, n0 = bx * 128;

    float acc[4][8];
    #pragma unroll
    for (int i = 0; i < 4; ++i)
        #pragma unroll
        for (int j = 0; j < 8; ++j) acc[i][j] = 0.f;

    const int ao = tid >> 2, aq = tid & 3;
    const int bkr = tid >> 5, bc = (tid & 31) * 4;

    for (int k0 = 0; k0 < CI_; k0 += 32) {
        *(float4*)&As[ao][aq * 8]     = *(const float4*)&w_w[(size_t)(r0 + ao) * CI_ + k0 + aq * 8];
        *(float4*)&As[ao][aq * 8 + 4] = *(const float4*)&w_w[(size_t)(r0 + ao) * CI_ + k0 + aq * 8 + 4];
        #pragma unroll
        for (int i = 0; i < 4; ++i) {
            const int kk = bkr + i * 8;
            *(float4*)&Bs[kk][bc] = *(const float4*)&y[((size_t)b * CI_ + k0 + kk) * N_ + n0 + bc];
        }
        __syncthreads();
        #pragma unroll
        for (int k = 0; k < 32; ++k) {
            float a[4];
            #pragma unroll
            for (int i = 0; i < 4; ++i) a[i] = As[ty * 4 + i][k];
            const float4 b0 = *(const float4*)&Bs[k][tx * 8];
            const float4 b1 = *(const float4*)&Bs[k][tx * 8 + 4];
            const float bb[8] = {b0.x, b0.y, b0.z, b0.w, b1.x, b1.y, b1.z, b1.w};
            #pragma unroll
            for (int i = 0; i < 4; ++i)
                #pragma unroll
                for (int j = 0; j < 8; ++j)
                    acc[i][j] = fmaf(a[i], bb[j], acc[i][j]);
        }
        __syncthreads();
    }

    #pragma unroll
    for (int i = 0; i < 4; ++i) {
        const int c = r0 + ty * 4 + i;
        const float sc = bn_g[c] * rsqrtf(bn_v[c] + 1e-5f);
        const float bb = bn_b[c], mn = bn_m[c], wb = w_b[c];
        const size_t base = ((size_t)b * C_ + c) * N_ + n0 + tx * 8;
        const float4 x0 = *(const float4*)&x[base];
        const float4 x1 = *(const float4*)&x[base + 4];
        const float xr[8] = {x0.x, x0.y, x0.z, x0.w, x1.x, x1.y, x1.z, x1.w};
        float o[8];
        #pragma unroll
        for (int j = 0; j < 8; ++j)
            o[j] = fmaf(acc[i][j] + wb - mn, sc, bb) + xr[j];
        float4 v0 = {o[0], o[1], o[2], o[3]};
        float4 v1 = {o[4], o[5], o[6], o[7]};
        *(float4*)&out[base]     = v0;
        *(float4*)&out[base + 4] = v1;
    }
}

// ===========================================================================
extern "C" void kernel_launch(void* const* d_in, const int* in_sizes, int n_in,
                              void* d_out, int out_size, void* d_ws, size_t ws_size,
                              hipStream_t stream) {
    const float* x    = (const float*)d_in[0];
    const float* g_w  = (const float*)d_in[1];
    const float* g_b  = (const float*)d_in[2];
    const float* th_w = (const float*)d_in[3];
    const float* th_b = (const float*)d_in[4];
    const float* ph_w = (const float*)d_in[5];
    const float* ph_b = (const float*)d_in[6];
    const float* w_w  = (const float*)d_in[7];
    const float* w_b  = (const float*)d_in[8];
    const float* bn_g = (const float*)d_in[9];
    const float* bn_b = (const float*)d_in[10];
    const float* bn_m = (const float*)d_in[11];
    const float* bn_v = (const float*)d_in[12];
    float* out = (float*)d_out;

    _Float16* thT = (_Float16*)d_ws;                       // 8*4096*256 f16 = 16 MB
    _Float16* phT = thT + (size_t)B_ * N_ * CI_;           // 8*1024*256 f16 =  4 MB
    _Float16* g16 = phT + (size_t)B_ * M_ * CI_;           //                  4 MB
    float*    yb  = (float*)(g16 + (size_t)B_ * M_ * CI_); // 8*256*4096 f32 = 32 MB (56 MB total)

    dim3 blk(16, 16);
    proj_kernel<<<dim3(32, 12, 8), blk, 0, stream>>>(x, g_w, g_b, th_w, th_b, ph_w, ph_b,
                                                     thT, phT, g16);
    attn_kernel<<<dim3(64, 8), dim3(256), 0, stream>>>(thT, phT, g16, yb);
    out_kernel<<<dim3(32, 8, 8), blk, 0, stream>>>(yb, w_w, w_b, bn_g, bn_b, bn_m, bn_v,
                                                   x, out);
}

// Round 4
// 526.588 us; speedup vs baseline: 2.8858x; 1.6605x over previous
//
#include <hip/hip_runtime.h>
#include <cmath>

// ---------------------------------------------------------------------------
// NonLocalBlock round 4: everything matmul-shaped on f16 MFMA (fp32 accum).
//  pre:  wAll[768][512] f16 (g,theta,phi stacked), w16[512][256] f16,
//        xT[b][n][c] f16 (transposed, K-contiguous)
//  K1:   proj GEMM 64x128xK512 tiles -> thT[b][n][c], phT[b][m][c], g16[b][ci][m]
//        (maxpool fused in-register via shfl)
//  K2:   flash attention (unchanged core) -> y16[b][n][ci] f16
//  K3:   out GEMM 64x128xK256 + bias + BN + residual -> out fp32
// ---------------------------------------------------------------------------

#define B_  8
#define C_  512
#define CI_ 256
#define N_  4096   // 64*64
#define M_  1024   // 32*32

typedef _Float16 half8 __attribute__((ext_vector_type(8)));
typedef _Float16 half4 __attribute__((ext_vector_type(4)));
typedef float    f32x4 __attribute__((ext_vector_type(4)));

// ===========================================================================
// K0a: weights -> fp16.  wAll rows: [0,256)=g, [256,512)=theta, [512,768)=phi
// ===========================================================================
__global__ __launch_bounds__(256) void wconv_kernel(
    const float* __restrict__ g_w, const float* __restrict__ th_w,
    const float* __restrict__ ph_w, const float* __restrict__ w_w,
    _Float16* __restrict__ wAll, _Float16* __restrict__ w16)
{
    const int i = blockIdx.x * 256 + threadIdx.x;
    if (i < 768 * 512) {
        const int o = i >> 9, c = i & 511;
        const float v = (o < 256) ? g_w[o * 512 + c]
                      : (o < 512) ? th_w[(o - 256) * 512 + c]
                                  : ph_w[(o - 512) * 512 + c];
        wAll[i] = (_Float16)v;
    } else {
        const int j = i - 768 * 512;
        w16[j] = (_Float16)w_w[j];
    }
}

// ===========================================================================
// K0b: xT[b][n][c] f16 from x[b][c][n] f32.  Tile [64c][64n] via LDS.
// ===========================================================================
__global__ __launch_bounds__(256) void xt_kernel(
    const float* __restrict__ x, _Float16* __restrict__ xT)
{
    __shared__ float Ls[64][68];
    const int t = threadIdx.x;
    const int n0 = blockIdx.x * 64, c0 = blockIdx.y * 64, b = blockIdx.z;

    const int row = t >> 4, coln = (t & 15) * 4;
    #pragma unroll
    for (int p = 0; p < 4; ++p) {
        const int c = p * 16 + row;
        *(float4*)&Ls[c][coln] = *(const float4*)&x[((size_t)b * C_ + c0 + c) * N_ + n0 + coln];
    }
    __syncthreads();
    const int nr = t >> 2, cq = (t & 3) * 16;
    _Float16 hv[16];
    #pragma unroll
    for (int j = 0; j < 16; ++j) hv[j] = (_Float16)Ls[cq + j][nr];
    _Float16* dst = &xT[((size_t)b * N_ + n0 + nr) * C_ + c0 + cq];
    *(half8*)&dst[0] = *(half8*)&hv[0];
    *(half8*)&dst[8] = *(half8*)&hv[8];
}

// ===========================================================================
// K1: proj GEMM on MFMA. Block = 64 out-rows x 128 n, K=512 in steps of 64.
// grid (32 n-tiles, 12 row-tiles, 8 b). rt<4: g (pool), rt<8: theta, else phi (pool).
// Wave w owns out-rows w*16..+15; 8 col frags of 16.
// Frag maps: A row=l15,k=lg*8+i (load);  C/D col=l15(n), row=lg*4+reg(out-c).
// ===========================================================================
__global__ __launch_bounds__(256) void proj_kernel(
    const _Float16* __restrict__ xT, const _Float16* __restrict__ wAll,
    const float* __restrict__ g_b, const float* __restrict__ th_b,
    const float* __restrict__ ph_b,
    _Float16* __restrict__ thT, _Float16* __restrict__ phT, _Float16* __restrict__ g16)
{
    __shared__ __align__(16) char smem[27648];
    _Float16 (*Ws)[72] = (_Float16(*)[72])smem;            // 64 x 72  = 9216 B
    _Float16 (*Xs)[72] = (_Float16(*)[72])(smem + 9216);   // 128 x 72 = 18432 B
    _Float16 (*Yt)[72] = (_Float16(*)[72])smem;            // theta epi: 128 x 72
    _Float16 (*Pp)[72] = (_Float16(*)[72])smem;            // phi epi:   32 x 72
    _Float16 (*Pg)[40] = (_Float16(*)[40])smem;            // g epi:     64 x 40

    const int t = threadIdx.x;
    const int w = t >> 6, l = t & 63, l15 = l & 15, lg = l >> 4;
    const int bx = blockIdx.x, rt = blockIdx.y, b = blockIdx.z;
    const int r0 = rt * 64, n0 = bx * 128;

    f32x4 acc[8];
    #pragma unroll
    for (int f = 0; f < 8; ++f) acc[f] = (f32x4){0.f, 0.f, 0.f, 0.f};

    const int warow = t >> 2, wakq = (t & 3) * 16;
    const int xrow = t >> 1,  xkq = (t & 1) * 32;

    #pragma unroll 1
    for (int k0 = 0; k0 < C_; k0 += 64) {
        __syncthreads();
        {
            const _Float16* src = &wAll[(size_t)(r0 + warow) * C_ + k0 + wakq];
            *(half8*)&Ws[warow][wakq]     = *(const half8*)&src[0];
            *(half8*)&Ws[warow][wakq + 8] = *(const half8*)&src[8];
            const _Float16* xs = &xT[((size_t)b * N_ + n0 + xrow) * C_ + k0 + xkq];
            *(half8*)&Xs[xrow][xkq]      = *(const half8*)&xs[0];
            *(half8*)&Xs[xrow][xkq + 8]  = *(const half8*)&xs[8];
            *(half8*)&Xs[xrow][xkq + 16] = *(const half8*)&xs[16];
            *(half8*)&Xs[xrow][xkq + 24] = *(const half8*)&xs[24];
        }
        __syncthreads();
        #pragma unroll
        for (int ks = 0; ks < 2; ++ks) {
            half8 a = *(half8*)&Ws[w * 16 + l15][ks * 32 + lg * 8];
            #pragma unroll
            for (int f = 0; f < 8; ++f) {
                half8 bb = *(half8*)&Xs[f * 16 + l15][ks * 32 + lg * 8];
                acc[f] = __builtin_amdgcn_mfma_f32_16x16x32_f16(a, bb, acc[f], 0, 0, 0);
            }
        }
    }

    // bias (per out-channel = rows of C/D frag)
    {
        const float* Bp = (rt < 4) ? g_b : (rt < 8) ? th_b : ph_b;
        const int coff = (rt < 4) ? 0 : (rt < 8) ? 256 : 512;
        float bias[4];
        #pragma unroll
        for (int r = 0; r < 4; ++r) bias[r] = Bp[r0 - coff + w * 16 + lg * 4 + r];
        #pragma unroll
        for (int f = 0; f < 8; ++f)
            #pragma unroll
            for (int r = 0; r < 4; ++r) acc[f][r] += bias[r];
    }

    if (rt >= 4 && rt < 8) {
        // ---- theta: thT[b][n][c], coalesced via LDS ----
        const int c0 = r0 - 256;
        __syncthreads();
        #pragma unroll
        for (int f = 0; f < 8; ++f) {
            half4 hv = { (_Float16)acc[f][0], (_Float16)acc[f][1],
                         (_Float16)acc[f][2], (_Float16)acc[f][3] };
            *(half4*)&Yt[f * 16 + l15][w * 16 + lg * 4] = hv;
        }
        __syncthreads();
        const int nr = t >> 1, oq = (t & 1) * 32;
        _Float16* dst = &thT[((size_t)b * N_ + n0 + nr) * CI_ + c0 + oq];
        #pragma unroll
        for (int j = 0; j < 4; ++j)
            *(half8*)&dst[j * 8] = *(half8*)&Yt[nr][oq + j * 8];
    } else {
        // ---- g / phi: 2x2 maxpool. nl = f*16+l15; rows h=2bx (f<4), 2bx+1 (f>=4).
        float pool[4][4];
        #pragma unroll
        for (int f = 0; f < 4; ++f)
            #pragma unroll
            for (int r = 0; r < 4; ++r) {
                const float v0 = acc[f][r], v1 = acc[f + 4][r];
                const float h0 = fmaxf(v0, __shfl_xor(v0, 1));
                const float h1 = fmaxf(v1, __shfl_xor(v1, 1));
                pool[f][r] = fmaxf(h0, h1);   // valid on even l15
            }
        __syncthreads();
        const bool isphi = (rt >= 8);
        const int c0 = isphi ? r0 - 512 : r0;
        if ((l15 & 1) == 0) {
            const int Wl = l15 >> 1;
            if (isphi) {
                #pragma unroll
                for (int f = 0; f < 4; ++f) {
                    half4 hv = { (_Float16)pool[f][0], (_Float16)pool[f][1],
                                 (_Float16)pool[f][2], (_Float16)pool[f][3] };
                    *(half4*)&Pp[f * 8 + Wl][w * 16 + lg * 4] = hv;
                }
            } else {
                #pragma unroll
                for (int f = 0; f < 4; ++f)
                    #pragma unroll
                    for (int r = 0; r < 4; ++r)
                        Pg[w * 16 + lg * 4 + r][f * 8 + Wl] = (_Float16)pool[f][r];
            }
        }
        __syncthreads();
        if (isphi) {
            const int row = t >> 3, cqq = (t & 7) * 8;   // 32 m-rows x 64 c
            *(half8*)&phT[((size_t)b * M_ + bx * 32 + row) * CI_ + c0 + cqq] =
                *(half8*)&Pp[row][cqq];
        } else {
            const int row = t >> 2, mq = (t & 3) * 8;    // 64 ci-rows x 32 m
            *(half8*)&g16[((size_t)b * CI_ + r0 + row) * M_ + bx * 32 + mq] =
                *(half8*)&Pg[row][mq];
        }
    }
}

// ===========================================================================
// K2: flash attention on mfma_f32_16x16x32_f16 (core unchanged, verified).
// Output now y16[b][n][ci] fp16 (K-contiguous for K3).
// ===========================================================================
__global__ __launch_bounds__(256) void attn_kernel(
    const _Float16* __restrict__ thT, const _Float16* __restrict__ phT,
    const _Float16* __restrict__ g16, _Float16* __restrict__ y16)
{
    __shared__ __align__(16) char smem[61440];
    _Float16 (*Tl)[264] = (_Float16(*)[264])smem;                 // 64x264 f16
    _Float16 (*Ph)[72]  = (_Float16(*)[72])(smem + 33792);        // 64x72
    _Float16 (*Gl)[72]  = (_Float16(*)[72])(smem + 43008);        // 64x72
    _Float16 (*Pl)[72]  = (_Float16(*)[72])(smem + 52224);        // 64x72
    float    (*Yb)[69]  = (float(*)[69])(smem + 33792);           // 64x69 f32 overlay

    const int t = threadIdx.x;
    const int w = t >> 6, l = t & 63;
    const int l15 = l & 15, lg = l >> 4;
    const int n0 = blockIdx.x * 64;
    const int b  = blockIdx.y;

    {
        const int row = t >> 2, cq = (t & 3) * 64;
        const _Float16* src = &thT[((size_t)b * N_ + n0 + row) * CI_ + cq];
        #pragma unroll
        for (int i = 0; i < 8; ++i)
            *(half8*)&Tl[row][cq + 8 * i] = *(const half8*)&src[8 * i];
    }

    f32x4 yacc[16];
    #pragma unroll
    for (int i = 0; i < 16; ++i) yacc[i] = (f32x4){0.f, 0.f, 0.f, 0.f};
    float m_run[4] = {-INFINITY, -INFINITY, -INFINITY, -INFINITY};
    float l_run[4] = {0.f, 0.f, 0.f, 0.f};

    const int srow = t >> 2, ssq = (t & 3) * 16;

    #pragma unroll 1
    for (int mt = 0; mt < 16; ++mt) {
        const int m0 = mt * 64;
        f32x4 sf[4];
        #pragma unroll
        for (int i = 0; i < 4; ++i) sf[i] = (f32x4){0.f, 0.f, 0.f, 0.f};

        #pragma unroll 1
        for (int cch = 0; cch < 4; ++cch) {
            __syncthreads();
            const _Float16* src = &phT[((size_t)b * M_ + m0 + srow) * CI_ + cch * 64 + ssq];
            *(half8*)&Ph[srow][ssq]     = *(const half8*)&src[0];
            *(half8*)&Ph[srow][ssq + 8] = *(const half8*)&src[8];
            __syncthreads();
            #pragma unroll
            for (int ks = 0; ks < 2; ++ks) {
                half8 a = *(half8*)&Tl[w * 16 + l15][cch * 64 + ks * 32 + lg * 8];
                #pragma unroll
                for (int mf = 0; mf < 4; ++mf) {
                    half8 bb = *(half8*)&Ph[mf * 16 + l15][ks * 32 + lg * 8];
                    sf[mf] = __builtin_amdgcn_mfma_f32_16x16x32_f16(a, bb, sf[mf], 0, 0, 0);
                }
            }
        }

        float sc[4];
        #pragma unroll
        for (int r = 0; r < 4; ++r) {
            float mx = fmaxf(fmaxf(sf[0][r], sf[1][r]), fmaxf(sf[2][r], sf[3][r]));
            #pragma unroll
            for (int off = 1; off < 16; off <<= 1) mx = fmaxf(mx, __shfl_xor(mx, off, 64));
            const float mnew = fmaxf(m_run[r], mx);
            sc[r] = __expf(m_run[r] - mnew);
            float sum = 0.f;
            #pragma unroll
            for (int mf = 0; mf < 4; ++mf) {
                const float p = __expf(sf[mf][r] - mnew);
                Pl[w * 16 + lg * 4 + r][mf * 16 + l15] = (_Float16)p;
                sum += p;
            }
            #pragma unroll
            for (int off = 1; off < 16; off <<= 1) sum += __shfl_xor(sum, off, 64);
            l_run[r] = l_run[r] * sc[r] + sum;
            m_run[r] = mnew;
        }
        #pragma unroll
        for (int i = 0; i < 16; ++i) {
            yacc[i][0] *= sc[0]; yacc[i][1] *= sc[1];
            yacc[i][2] *= sc[2]; yacc[i][3] *= sc[3];
        }

        #pragma unroll 1
        for (int cc = 0; cc < 4; ++cc) {
            __syncthreads();
            const _Float16* gs = &g16[((size_t)b * CI_ + cc * 64 + srow) * M_ + m0 + ssq];
            *(half8*)&Gl[srow][ssq]     = *(const half8*)&gs[0];
            *(half8*)&Gl[srow][ssq + 8] = *(const half8*)&gs[8];
            __syncthreads();
            half8 pa0 = *(half8*)&Pl[w * 16 + l15][lg * 8];
            half8 pa1 = *(half8*)&Pl[w * 16 + l15][32 + lg * 8];
            #pragma unroll
            for (int cf = 0; cf < 4; ++cf) {
                half8 b0 = *(half8*)&Gl[cf * 16 + l15][lg * 8];
                half8 b1 = *(half8*)&Gl[cf * 16 + l15][32 + lg * 8];
                yacc[cc * 4 + cf] = __builtin_amdgcn_mfma_f32_16x16x32_f16(pa0, b0, yacc[cc * 4 + cf], 0, 0, 0);
                yacc[cc * 4 + cf] = __builtin_amdgcn_mfma_f32_16x16x32_f16(pa1, b1, yacc[cc * 4 + cf], 0, 0, 0);
            }
        }
    }

    // ---- epilogue: y16[b][n][ci] fp16, coalesced via LDS ----
    float linv[4];
    #pragma unroll
    for (int r = 0; r < 4; ++r) linv[r] = 1.f / l_run[r];
    #pragma unroll 1
    for (int cq = 0; cq < 4; ++cq) {
        __syncthreads();
        #pragma unroll
        for (int f = 0; f < 4; ++f)
            #pragma unroll
            for (int r = 0; r < 4; ++r)
                Yb[w * 16 + lg * 4 + r][f * 16 + l15] = yacc[cq * 4 + f][r] * linv[r];
        __syncthreads();
        const int row = t >> 2, cil = (t & 3) * 16;
        _Float16 hv[16];
        #pragma unroll
        for (int j = 0; j < 16; ++j) hv[j] = (_Float16)Yb[row][cil + j];
        _Float16* dst = &y16[((size_t)b * N_ + n0 + row) * CI_ + cq * 64 + cil];
        *(half8*)&dst[0] = *(half8*)&hv[0];
        *(half8*)&dst[8] = *(half8*)&hv[8];
    }
}

// ===========================================================================
// K3: out conv on MFMA + bias + BN + residual. Block = 64 c x 128 n, K=256.
// ===========================================================================
__global__ __launch_bounds__(256) void out_kernel(
    const _Float16* __restrict__ y16, const _Float16* __restrict__ w16,
    const float* __restrict__ w_b,
    const float* __restrict__ bn_g, const float* __restrict__ bn_b,
    const float* __restrict__ bn_m, const float* __restrict__ bn_v,
    const float* __restrict__ x, float* __restrict__ out)
{
    __shared__ __align__(16) char smem[33792];
    _Float16 (*Ws)[72] = (_Float16(*)[72])smem;            // 64 x 72
    _Float16 (*Ys)[72] = (_Float16(*)[72])(smem + 9216);   // 128 x 72
    float    (*Yt)[132] = (float(*)[132])smem;             // 64 x 132 f32 overlay

    const int t = threadIdx.x;
    const int w = t >> 6, l = t & 63, l15 = l & 15, lg = l >> 4;
    const int bx = blockIdx.x, by = blockIdx.y, b = blockIdx.z;
    const int r0 = by * 64, n0 = bx * 128;

    f32x4 acc[8];
    #pragma unroll
    for (int f = 0; f < 8; ++f) acc[f] = (f32x4){0.f, 0.f, 0.f, 0.f};

    const int warow = t >> 2, wakq = (t & 3) * 16;
    const int yrow = t >> 1,  ykq = (t & 1) * 32;

    #pragma unroll 1
    for (int k0 = 0; k0 < CI_; k0 += 64) {
        __syncthreads();
        {
            const _Float16* src = &w16[(size_t)(r0 + warow) * CI_ + k0 + wakq];
            *(half8*)&Ws[warow][wakq]     = *(const half8*)&src[0];
            *(half8*)&Ws[warow][wakq + 8] = *(const half8*)&src[8];
            const _Float16* ys = &y16[((size_t)b * N_ + n0 + yrow) * CI_ + k0 + ykq];
            *(half8*)&Ys[yrow][ykq]      = *(const half8*)&ys[0];
            *(half8*)&Ys[yrow][ykq + 8]  = *(const half8*)&ys[8];
            *(half8*)&Ys[yrow][ykq + 16] = *(const half8*)&ys[16];
            *(half8*)&Ys[yrow][ykq + 24] = *(const half8*)&ys[24];
        }
        __syncthreads();
        #pragma unroll
        for (int ks = 0; ks < 2; ++ks) {
            half8 a = *(half8*)&Ws[w * 16 + l15][ks * 32 + lg * 8];
            #pragma unroll
            for (int f = 0; f < 8; ++f) {
                half8 bb = *(half8*)&Ys[f * 16 + l15][ks * 32 + lg * 8];
                acc[f] = __builtin_amdgcn_mfma_f32_16x16x32_f16(a, bb, acc[f], 0, 0, 0);
            }
        }
    }

    // BN params for the 4 frag rows
    float scp[4], shp[4];
    #pragma unroll
    for (int r = 0; r < 4; ++r) {
        const int c = r0 + w * 16 + lg * 4 + r;
        const float s = bn_g[c] * rsqrtf(bn_v[c] + 1e-5f);
        scp[r] = s;
        shp[r] = bn_b[c] + (w_b[c] - bn_m[c]) * s;
    }
    __syncthreads();
    #pragma unroll
    for (int f = 0; f < 8; ++f)
        #pragma unroll
        for (int r = 0; r < 4; ++r)
            Yt[w * 16 + lg * 4 + r][f * 16 + l15] = acc[f][r] * scp[r] + shp[r];
    __syncthreads();

    const int prow = t >> 5, nq = (t & 31) * 4;
    #pragma unroll
    for (int p = 0; p < 8; ++p) {
        const int row = p * 8 + prow;
        const size_t base = ((size_t)b * C_ + r0 + row) * N_ + n0 + nq;
        const float4 xr = *(const float4*)&x[base];
        float4 v = *(float4*)&Yt[row][nq];
        v.x += xr.x; v.y += xr.y; v.z += xr.z; v.w += xr.w;
        *(float4*)&out[base] = v;
    }
}

// ===========================================================================
extern "C" void kernel_launch(void* const* d_in, const int* in_sizes, int n_in,
                              void* d_out, int out_size, void* d_ws, size_t ws_size,
                              hipStream_t stream) {
    const float* x    = (const float*)d_in[0];
    const float* g_w  = (const float*)d_in[1];
    const float* g_b  = (const float*)d_in[2];
    const float* th_w = (const float*)d_in[3];
    const float* th_b = (const float*)d_in[4];
    const float* ph_w = (const float*)d_in[5];
    const float* ph_b = (const float*)d_in[6];
    const float* w_w  = (const float*)d_in[7];
    const float* w_b  = (const float*)d_in[8];
    const float* bn_g = (const float*)d_in[9];
    const float* bn_b = (const float*)d_in[10];
    const float* bn_m = (const float*)d_in[11];
    const float* bn_v = (const float*)d_in[12];
    float* out = (float*)d_out;

    _Float16* xT   = (_Float16*)d_ws;                      // 8*4096*512 = 32 MB
    _Float16* wAll = xT + (size_t)B_ * N_ * C_;            // 768*512
    _Float16* w16  = wAll + 768 * 512;                     // 512*256
    _Float16* thT  = w16 + 512 * 256;                      // 16 MB
    _Float16* phT  = thT + (size_t)B_ * N_ * CI_;          // 4 MB
    _Float16* g16  = phT + (size_t)B_ * M_ * CI_;          // 4 MB
    _Float16* y16  = g16 + (size_t)B_ * M_ * CI_;          // 16 MB (total ~76.5 MB)

    wconv_kernel<<<2048, 256, 0, stream>>>(g_w, th_w, ph_w, w_w, wAll, w16);
    xt_kernel<<<dim3(64, 8, 8), 256, 0, stream>>>(x, xT);
    proj_kernel<<<dim3(32, 12, 8), 256, 0, stream>>>(xT, wAll, g_b, th_b, ph_b,
                                                     thT, phT, g16);
    attn_kernel<<<dim3(64, 8), 256, 0, stream>>>(thT, phT, g16, y16);
    out_kernel<<<dim3(32, 8, 8), 256, 0, stream>>>(y16, w16, w_b, bn_g, bn_b, bn_m, bn_v,
                                                   x, out);
}

// Round 6
// 339.495 us; speedup vs baseline: 4.4762x; 1.5511x over previous
//
#include <hip/hip_runtime.h>
#include <cmath>

// ---------------------------------------------------------------------------
// NonLocalBlock round 5 (resubmit): fix yacc scratch spill in attn (rule #20 —
// runtime-indexed ext_vector arrays go to local memory). PV chunk loop and
// epilogue loop are now fully unrolled so all yacc indices are static.
// Everything else identical to round 4.
// ---------------------------------------------------------------------------

#define B_  8
#define C_  512
#define CI_ 256
#define N_  4096   // 64*64
#define M_  1024   // 32*32

typedef _Float16 half8 __attribute__((ext_vector_type(8)));
typedef _Float16 half4 __attribute__((ext_vector_type(4)));
typedef float    f32x4 __attribute__((ext_vector_type(4)));

// ===========================================================================
// K0a: weights -> fp16.  wAll rows: [0,256)=g, [256,512)=theta, [512,768)=phi
// ===========================================================================
__global__ __launch_bounds__(256) void wconv_kernel(
    const float* __restrict__ g_w, const float* __restrict__ th_w,
    const float* __restrict__ ph_w, const float* __restrict__ w_w,
    _Float16* __restrict__ wAll, _Float16* __restrict__ w16)
{
    const int i = blockIdx.x * 256 + threadIdx.x;
    if (i < 768 * 512) {
        const int o = i >> 9, c = i & 511;
        const float v = (o < 256) ? g_w[o * 512 + c]
                      : (o < 512) ? th_w[(o - 256) * 512 + c]
                                  : ph_w[(o - 512) * 512 + c];
        wAll[i] = (_Float16)v;
    } else {
        const int j = i - 768 * 512;
        w16[j] = (_Float16)w_w[j];
    }
}

// ===========================================================================
// K0b: xT[b][n][c] f16 from x[b][c][n] f32.  Tile [64c][64n] via LDS.
// ===========================================================================
__global__ __launch_bounds__(256) void xt_kernel(
    const float* __restrict__ x, _Float16* __restrict__ xT)
{
    __shared__ float Ls[64][68];
    const int t = threadIdx.x;
    const int n0 = blockIdx.x * 64, c0 = blockIdx.y * 64, b = blockIdx.z;

    const int row = t >> 4, coln = (t & 15) * 4;
    #pragma unroll
    for (int p = 0; p < 4; ++p) {
        const int c = p * 16 + row;
        *(float4*)&Ls[c][coln] = *(const float4*)&x[((size_t)b * C_ + c0 + c) * N_ + n0 + coln];
    }
    __syncthreads();
    const int nr = t >> 2, cq = (t & 3) * 16;
    _Float16 hv[16];
    #pragma unroll
    for (int j = 0; j < 16; ++j) hv[j] = (_Float16)Ls[cq + j][nr];
    _Float16* dst = &xT[((size_t)b * N_ + n0 + nr) * C_ + c0 + cq];
    *(half8*)&dst[0] = *(half8*)&hv[0];
    *(half8*)&dst[8] = *(half8*)&hv[8];
}

// ===========================================================================
// K1: proj GEMM on MFMA. Block = 64 out-rows x 128 n, K=512 in steps of 64.
// grid (32 n-tiles, 12 row-tiles, 8 b). rt<4: g (pool), rt<8: theta, else phi (pool).
// ===========================================================================
__global__ __launch_bounds__(256) void proj_kernel(
    const _Float16* __restrict__ xT, const _Float16* __restrict__ wAll,
    const float* __restrict__ g_b, const float* __restrict__ th_b,
    const float* __restrict__ ph_b,
    _Float16* __restrict__ thT, _Float16* __restrict__ phT, _Float16* __restrict__ g16)
{
    __shared__ __align__(16) char smem[27648];
    _Float16 (*Ws)[72] = (_Float16(*)[72])smem;            // 64 x 72  = 9216 B
    _Float16 (*Xs)[72] = (_Float16(*)[72])(smem + 9216);   // 128 x 72 = 18432 B
    _Float16 (*Yt)[72] = (_Float16(*)[72])smem;            // theta epi: 128 x 72
    _Float16 (*Pp)[72] = (_Float16(*)[72])smem;            // phi epi:   32 x 72
    _Float16 (*Pg)[40] = (_Float16(*)[40])smem;            // g epi:     64 x 40

    const int t = threadIdx.x;
    const int w = t >> 6, l = t & 63, l15 = l & 15, lg = l >> 4;
    const int bx = blockIdx.x, rt = blockIdx.y, b = blockIdx.z;
    const int r0 = rt * 64, n0 = bx * 128;

    f32x4 acc[8];
    #pragma unroll
    for (int f = 0; f < 8; ++f) acc[f] = (f32x4){0.f, 0.f, 0.f, 0.f};

    const int warow = t >> 2, wakq = (t & 3) * 16;
    const int xrow = t >> 1,  xkq = (t & 1) * 32;

    #pragma unroll 1
    for (int k0 = 0; k0 < C_; k0 += 64) {
        __syncthreads();
        {
            const _Float16* src = &wAll[(size_t)(r0 + warow) * C_ + k0 + wakq];
            *(half8*)&Ws[warow][wakq]     = *(const half8*)&src[0];
            *(half8*)&Ws[warow][wakq + 8] = *(const half8*)&src[8];
            const _Float16* xs = &xT[((size_t)b * N_ + n0 + xrow) * C_ + k0 + xkq];
            *(half8*)&Xs[xrow][xkq]      = *(const half8*)&xs[0];
            *(half8*)&Xs[xrow][xkq + 8]  = *(const half8*)&xs[8];
            *(half8*)&Xs[xrow][xkq + 16] = *(const half8*)&xs[16];
            *(half8*)&Xs[xrow][xkq + 24] = *(const half8*)&xs[24];
        }
        __syncthreads();
        #pragma unroll
        for (int ks = 0; ks < 2; ++ks) {
            half8 a = *(half8*)&Ws[w * 16 + l15][ks * 32 + lg * 8];
            #pragma unroll
            for (int f = 0; f < 8; ++f) {
                half8 bb = *(half8*)&Xs[f * 16 + l15][ks * 32 + lg * 8];
                acc[f] = __builtin_amdgcn_mfma_f32_16x16x32_f16(a, bb, acc[f], 0, 0, 0);
            }
        }
    }

    // bias (per out-channel = rows of C/D frag)
    {
        const float* Bp = (rt < 4) ? g_b : (rt < 8) ? th_b : ph_b;
        const int coff = (rt < 4) ? 0 : (rt < 8) ? 256 : 512;
        float bias[4];
        #pragma unroll
        for (int r = 0; r < 4; ++r) bias[r] = Bp[r0 - coff + w * 16 + lg * 4 + r];
        #pragma unroll
        for (int f = 0; f < 8; ++f)
            #pragma unroll
            for (int r = 0; r < 4; ++r) acc[f][r] += bias[r];
    }

    if (rt >= 4 && rt < 8) {
        // ---- theta: thT[b][n][c], coalesced via LDS ----
        const int c0 = r0 - 256;
        __syncthreads();
        #pragma unroll
        for (int f = 0; f < 8; ++f) {
            half4 hv = { (_Float16)acc[f][0], (_Float16)acc[f][1],
                         (_Float16)acc[f][2], (_Float16)acc[f][3] };
            *(half4*)&Yt[f * 16 + l15][w * 16 + lg * 4] = hv;
        }
        __syncthreads();
        const int nr = t >> 1, oq = (t & 1) * 32;
        _Float16* dst = &thT[((size_t)b * N_ + n0 + nr) * CI_ + c0 + oq];
        #pragma unroll
        for (int j = 0; j < 4; ++j)
            *(half8*)&dst[j * 8] = *(half8*)&Yt[nr][oq + j * 8];
    } else {
        // ---- g / phi: 2x2 maxpool. nl = f*16+l15; rows h=2bx (f<4), 2bx+1 (f>=4).
        float pool[4][4];
        #pragma unroll
        for (int f = 0; f < 4; ++f)
            #pragma unroll
            for (int r = 0; r < 4; ++r) {
                const float v0 = acc[f][r], v1 = acc[f + 4][r];
                const float h0 = fmaxf(v0, __shfl_xor(v0, 1));
                const float h1 = fmaxf(v1, __shfl_xor(v1, 1));
                pool[f][r] = fmaxf(h0, h1);   // valid on even l15
            }
        __syncthreads();
        const bool isphi = (rt >= 8);
        const int c0 = isphi ? r0 - 512 : r0;
        if ((l15 & 1) == 0) {
            const int Wl = l15 >> 1;
            if (isphi) {
                #pragma unroll
                for (int f = 0; f < 4; ++f) {
                    half4 hv = { (_Float16)pool[f][0], (_Float16)pool[f][1],
                                 (_Float16)pool[f][2], (_Float16)pool[f][3] };
                    *(half4*)&Pp[f * 8 + Wl][w * 16 + lg * 4] = hv;
                }
            } else {
                #pragma unroll
                for (int f = 0; f < 4; ++f)
                    #pragma unroll
                    for (int r = 0; r < 4; ++r)
                        Pg[w * 16 + lg * 4 + r][f * 8 + Wl] = (_Float16)pool[f][r];
            }
        }
        __syncthreads();
        if (isphi) {
            const int row = t >> 3, cqq = (t & 7) * 8;   // 32 m-rows x 64 c
            *(half8*)&phT[((size_t)b * M_ + bx * 32 + row) * CI_ + c0 + cqq] =
                *(half8*)&Pp[row][cqq];
        } else {
            const int row = t >> 2, mq = (t & 3) * 8;    // 64 ci-rows x 32 m
            *(half8*)&g16[((size_t)b * CI_ + r0 + row) * M_ + bx * 32 + mq] =
                *(half8*)&Pg[row][mq];
        }
    }
}

// ===========================================================================
// K2: flash attention on mfma_f32_16x16x32_f16.
// FIX: PV chunk loop and epilogue loop fully unrolled -> yacc stays in VGPRs.
// ===========================================================================
__global__ __launch_bounds__(256) void attn_kernel(
    const _Float16* __restrict__ thT, const _Float16* __restrict__ phT,
    const _Float16* __restrict__ g16, _Float16* __restrict__ y16)
{
    __shared__ __align__(16) char smem[61440];
    _Float16 (*Tl)[264] = (_Float16(*)[264])smem;                 // 64x264 f16
    _Float16 (*Ph)[72]  = (_Float16(*)[72])(smem + 33792);        // 64x72
    _Float16 (*Gl)[72]  = (_Float16(*)[72])(smem + 43008);        // 64x72
    _Float16 (*Pl)[72]  = (_Float16(*)[72])(smem + 52224);        // 64x72
    float    (*Yb)[69]  = (float(*)[69])(smem + 33792);           // 64x69 f32 overlay

    const int t = threadIdx.x;
    const int w = t >> 6, l = t & 63;
    const int l15 = l & 15, lg = l >> 4;
    const int n0 = blockIdx.x * 64;
    const int b  = blockIdx.y;

    {
        const int row = t >> 2, cq = (t & 3) * 64;
        const _Float16* src = &thT[((size_t)b * N_ + n0 + row) * CI_ + cq];
        #pragma unroll
        for (int i = 0; i < 8; ++i)
            *(half8*)&Tl[row][cq + 8 * i] = *(const half8*)&src[8 * i];
    }

    f32x4 yacc[16];
    #pragma unroll
    for (int i = 0; i < 16; ++i) yacc[i] = (f32x4){0.f, 0.f, 0.f, 0.f};
    float m_run[4] = {-INFINITY, -INFINITY, -INFINITY, -INFINITY};
    float l_run[4] = {0.f, 0.f, 0.f, 0.f};

    const int srow = t >> 2, ssq = (t & 3) * 16;

    #pragma unroll 1
    for (int mt = 0; mt < 16; ++mt) {
        const int m0 = mt * 64;
        f32x4 sf[4];
        #pragma unroll
        for (int i = 0; i < 4; ++i) sf[i] = (f32x4){0.f, 0.f, 0.f, 0.f};

        #pragma unroll 1
        for (int cch = 0; cch < 4; ++cch) {
            __syncthreads();
            const _Float16* src = &phT[((size_t)b * M_ + m0 + srow) * CI_ + cch * 64 + ssq];
            *(half8*)&Ph[srow][ssq]     = *(const half8*)&src[0];
            *(half8*)&Ph[srow][ssq + 8] = *(const half8*)&src[8];
            __syncthreads();
            #pragma unroll
            for (int ks = 0; ks < 2; ++ks) {
                half8 a = *(half8*)&Tl[w * 16 + l15][cch * 64 + ks * 32 + lg * 8];
                #pragma unroll
                for (int mf = 0; mf < 4; ++mf) {
                    half8 bb = *(half8*)&Ph[mf * 16 + l15][ks * 32 + lg * 8];
                    sf[mf] = __builtin_amdgcn_mfma_f32_16x16x32_f16(a, bb, sf[mf], 0, 0, 0);
                }
            }
        }

        float sc[4];
        #pragma unroll
        for (int r = 0; r < 4; ++r) {
            float mx = fmaxf(fmaxf(sf[0][r], sf[1][r]), fmaxf(sf[2][r], sf[3][r]));
            #pragma unroll
            for (int off = 1; off < 16; off <<= 1) mx = fmaxf(mx, __shfl_xor(mx, off, 64));
            const float mnew = fmaxf(m_run[r], mx);
            sc[r] = __expf(m_run[r] - mnew);
            float sum = 0.f;
            #pragma unroll
            for (int mf = 0; mf < 4; ++mf) {
                const float p = __expf(sf[mf][r] - mnew);
                Pl[w * 16 + lg * 4 + r][mf * 16 + l15] = (_Float16)p;
                sum += p;
            }
            #pragma unroll
            for (int off = 1; off < 16; off <<= 1) sum += __shfl_xor(sum, off, 64);
            l_run[r] = l_run[r] * sc[r] + sum;
            m_run[r] = mnew;
        }
        #pragma unroll
        for (int i = 0; i < 16; ++i) {
            yacc[i][0] *= sc[0]; yacc[i][1] *= sc[1];
            yacc[i][2] *= sc[2]; yacc[i][3] *= sc[3];
        }

        // ---- Y += P @ G^T over ci in 4 chunks of 64 (FULLY UNROLLED) ----
        #pragma unroll
        for (int cc = 0; cc < 4; ++cc) {
            __syncthreads();
            const _Float16* gs = &g16[((size_t)b * CI_ + cc * 64 + srow) * M_ + m0 + ssq];
            *(half8*)&Gl[srow][ssq]     = *(const half8*)&gs[0];
            *(half8*)&Gl[srow][ssq + 8] = *(const half8*)&gs[8];
            __syncthreads();
            half8 pa0 = *(half8*)&Pl[w * 16 + l15][lg * 8];
            half8 pa1 = *(half8*)&Pl[w * 16 + l15][32 + lg * 8];
            #pragma unroll
            for (int cf = 0; cf < 4; ++cf) {
                half8 b0 = *(half8*)&Gl[cf * 16 + l15][lg * 8];
                half8 b1 = *(half8*)&Gl[cf * 16 + l15][32 + lg * 8];
                yacc[cc * 4 + cf] = __builtin_amdgcn_mfma_f32_16x16x32_f16(pa0, b0, yacc[cc * 4 + cf], 0, 0, 0);
                yacc[cc * 4 + cf] = __builtin_amdgcn_mfma_f32_16x16x32_f16(pa1, b1, yacc[cc * 4 + cf], 0, 0, 0);
            }
        }
    }

    // ---- epilogue: y16[b][n][ci] fp16, coalesced via LDS (FULLY UNROLLED) ----
    float linv[4];
    #pragma unroll
    for (int r = 0; r < 4; ++r) linv[r] = 1.f / l_run[r];
    #pragma unroll
    for (int cq = 0; cq < 4; ++cq) {
        __syncthreads();
        #pragma unroll
        for (int f = 0; f < 4; ++f)
            #pragma unroll
            for (int r = 0; r < 4; ++r)
                Yb[w * 16 + lg * 4 + r][f * 16 + l15] = yacc[cq * 4 + f][r] * linv[r];
        __syncthreads();
        const int row = t >> 2, cil = (t & 3) * 16;
        _Float16 hv[16];
        #pragma unroll
        for (int j = 0; j < 16; ++j) hv[j] = (_Float16)Yb[row][cil + j];
        _Float16* dst = &y16[((size_t)b * N_ + n0 + row) * CI_ + cq * 64 + cil];
        *(half8*)&dst[0] = *(half8*)&hv[0];
        *(half8*)&dst[8] = *(half8*)&hv[8];
    }
}

// ===========================================================================
// K3: out conv on MFMA + bias + BN + residual. Block = 64 c x 128 n, K=256.
// ===========================================================================
__global__ __launch_bounds__(256) void out_kernel(
    const _Float16* __restrict__ y16, const _Float16* __restrict__ w16,
    const float* __restrict__ w_b,
    const float* __restrict__ bn_g, const float* __restrict__ bn_b,
    const float* __restrict__ bn_m, const float* __restrict__ bn_v,
    const float* __restrict__ x, float* __restrict__ out)
{
    __shared__ __align__(16) char smem[33792];
    _Float16 (*Ws)[72] = (_Float16(*)[72])smem;            // 64 x 72
    _Float16 (*Ys)[72] = (_Float16(*)[72])(smem + 9216);   // 128 x 72
    float    (*Yt)[132] = (float(*)[132])smem;             // 64 x 132 f32 overlay

    const int t = threadIdx.x;
    const int w = t >> 6, l = t & 63, l15 = l & 15, lg = l >> 4;
    const int bx = blockIdx.x, by = blockIdx.y, b = blockIdx.z;
    const int r0 = by * 64, n0 = bx * 128;

    f32x4 acc[8];
    #pragma unroll
    for (int f = 0; f < 8; ++f) acc[f] = (f32x4){0.f, 0.f, 0.f, 0.f};

    const int warow = t >> 2, wakq = (t & 3) * 16;
    const int yrow = t >> 1,  ykq = (t & 1) * 32;

    #pragma unroll 1
    for (int k0 = 0; k0 < CI_; k0 += 64) {
        __syncthreads();
        {
            const _Float16* src = &w16[(size_t)(r0 + warow) * CI_ + k0 + wakq];
            *(half8*)&Ws[warow][wakq]     = *(const half8*)&src[0];
            *(half8*)&Ws[warow][wakq + 8] = *(const half8*)&src[8];
            const _Float16* ys = &y16[((size_t)b * N_ + n0 + yrow) * CI_ + k0 + ykq];
            *(half8*)&Ys[yrow][ykq]      = *(const half8*)&ys[0];
            *(half8*)&Ys[yrow][ykq + 8]  = *(const half8*)&ys[8];
            *(half8*)&Ys[yrow][ykq + 16] = *(const half8*)&ys[16];
            *(half8*)&Ys[yrow][ykq + 24] = *(const half8*)&ys[24];
        }
        __syncthreads();
        #pragma unroll
        for (int ks = 0; ks < 2; ++ks) {
            half8 a = *(half8*)&Ws[w * 16 + l15][ks * 32 + lg * 8];
            #pragma unroll
            for (int f = 0; f < 8; ++f) {
                half8 bb = *(half8*)&Ys[f * 16 + l15][ks * 32 + lg * 8];
                acc[f] = __builtin_amdgcn_mfma_f32_16x16x32_f16(a, bb, acc[f], 0, 0, 0);
            }
        }
    }

    // BN params for the 4 frag rows
    float scp[4], shp[4];
    #pragma unroll
    for (int r = 0; r < 4; ++r) {
        const int c = r0 + w * 16 + lg * 4 + r;
        const float s = bn_g[c] * rsqrtf(bn_v[c] + 1e-5f);
        scp[r] = s;
        shp[r] = bn_b[c] + (w_b[c] - bn_m[c]) * s;
    }
    __syncthreads();
    #pragma unroll
    for (int f = 0; f < 8; ++f)
        #pragma unroll
        for (int r = 0; r < 4; ++r)
            Yt[w * 16 + lg * 4 + r][f * 16 + l15] = acc[f][r] * scp[r] + shp[r];
    __syncthreads();

    const int prow = t >> 5, nq = (t & 31) * 4;
    #pragma unroll
    for (int p = 0; p < 8; ++p) {
        const int row = p * 8 + prow;
        const size_t base = ((size_t)b * C_ + r0 + row) * N_ + n0 + nq;
        const float4 xr = *(const float4*)&x[base];
        float4 v = *(float4*)&Yt[row][nq];
        v.x += xr.x; v.y += xr.y; v.z += xr.z; v.w += xr.w;
        *(float4*)&out[base] = v;
    }
}

// ===========================================================================
extern "C" void kernel_launch(void* const* d_in, const int* in_sizes, int n_in,
                              void* d_out, int out_size, void* d_ws, size_t ws_size,
                              hipStream_t stream) {
    const float* x    = (const float*)d_in[0];
    const float* g_w  = (const float*)d_in[1];
    const float* g_b  = (const float*)d_in[2];
    const float* th_w = (const float*)d_in[3];
    const float* th_b = (const float*)d_in[4];
    const float* ph_w = (const float*)d_in[5];
    const float* ph_b = (const float*)d_in[6];
    const float* w_w  = (const float*)d_in[7];
    const float* w_b  = (const float*)d_in[8];
    const float* bn_g = (const float*)d_in[9];
    const float* bn_b = (const float*)d_in[10];
    const float* bn_m = (const float*)d_in[11];
    const float* bn_v = (const float*)d_in[12];
    float* out = (float*)d_out;

    _Float16* xT   = (_Float16*)d_ws;                      // 8*4096*512 = 32 MB
    _Float16* wAll = xT + (size_t)B_ * N_ * C_;            // 768*512
    _Float16* w16  = wAll + 768 * 512;                     // 512*256
    _Float16* thT  = w16 + 512 * 256;                      // 16 MB
    _Float16* phT  = thT + (size_t)B_ * N_ * CI_;          // 4 MB
    _Float16* g16  = phT + (size_t)B_ * M_ * CI_;          // 4 MB
    _Float16* y16  = g16 + (size_t)B_ * M_ * CI_;          // 16 MB (total ~76.5 MB)

    wconv_kernel<<<2048, 256, 0, stream>>>(g_w, th_w, ph_w, w_w, wAll, w16);
    xt_kernel<<<dim3(64, 8, 8), 256, 0, stream>>>(x, xT);
    proj_kernel<<<dim3(32, 12, 8), 256, 0, stream>>>(xT, wAll, g_b, th_b, ph_b,
                                                     thT, phT, g16);
    attn_kernel<<<dim3(64, 8), 256, 0, stream>>>(thT, phT, g16, y16);
    out_kernel<<<dim3(32, 8, 8), 256, 0, stream>>>(y16, w16, w_b, bn_g, bn_b, bn_m, bn_v,
                                                   x, out);
}